// Round 7
// baseline (233.344 us; speedup 1.0000x reference)
//
#include <hip/hip_runtime.h>
#include <math.h>

typedef __bf16 bf16x8 __attribute__((ext_vector_type(8)));
typedef float f32x4 __attribute__((ext_vector_type(4)));
typedef unsigned short u16;
typedef unsigned int u32;

#define S128 0.08838834764831845f       // 1/sqrt(128)
#define TWOPI_128 0.04908738521234052f  // 2*pi/128
#define MROWS 30016                     // 469*64 (padded row capacity)

// ---------------------------------------------------------------------------
// Device-global precomputed operands.
// g_wft: per (mod, ks) chunk of 12288 u16 = [plane2][gran4][col192][8],
//        intra-plane offsets XOR-swizzled with (gran<<4) (u16 units).
// g_gt : per ks chunk of 8192 u16 = [plane2][gran4][n128][8], same swz.
// g_fp : per freq k (0..95): {rotc, rots, avrfI, avrfT, bIre, bIim, bTre, bTim}
// g_S  : spectra hi/lo packed u32, layout [mod][ks6][khh4][row MROWS][8]
// ---------------------------------------------------------------------------
__device__ __align__(16) u16 g_wft[56 * 12288];
__device__ __align__(16) u16 g_gt[6 * 8192];
__device__ __align__(16) float g_fp[96 * 8];
__device__ __align__(16) u32 g_S[(size_t)2 * 6 * 4 * MROWS * 8];

__device__ __forceinline__ void split2(float v, u16& h, u16& l) {
  unsigned u = __float_as_uint(v);
  h = (u16)(u >> 16);
  float hf = __uint_as_float(u & 0xFFFF0000u);
  float lo = v - hf;
  unsigned ul = __float_as_uint(lo);
  l = (u16)((ul + 0x7FFFu + ((ul >> 16) & 1u)) >> 16);
}

__device__ __forceinline__ void gll16(const void* gsrc, void* ldst) {
  __builtin_amdgcn_global_load_lds(
      (const __attribute__((address_space(1))) unsigned int*)gsrc,
      (__attribute__((address_space(3))) unsigned int*)ldst, 16, 0, 0);
}

// ---------------------------------------------------------------------------
// Setup: WF = W @ F (ortho rfft matrix), bf16 hi/lo, k-granule-major chunks,
// granule XOR-swizzle baked into the global image.
// ---------------------------------------------------------------------------
__global__ void k_setup_wft(const float* __restrict__ Wimg,
                            const float* __restrict__ Wtxt, int Kimg, int Ktxt) {
  int gid = blockIdx.x * 256 + threadIdx.x;
  int imgn = Kimg * 96;
  if (gid >= imgn + Ktxt * 96) return;
  const float* Wrow;
  u16* base;
  int kloc, fq;
  if (gid < imgn) {
    kloc = gid / 96; fq = gid % 96;
    Wrow = Wimg + (size_t)kloc * 128;
    base = g_wft + (size_t)(kloc >> 5) * 12288;
  } else {
    int l = gid - imgn;
    kloc = l / 96; fq = l % 96;
    Wrow = Wtxt + (size_t)kloc * 128;
    base = g_wft + (size_t)(32 + (kloc >> 5)) * 12288;
  }
  float re = 0.f, im = 0.f;
  if (fq <= 64) {
    float sts, stc;
    sincosf(TWOPI_128 * (float)fq, &sts, &stc);   // step e^{-ia} = (stc, -sts)
    for (int d0 = 0; d0 < 128; d0 += 16) {
      int m = (fq * d0) & 127;
      float sa, ca;
      sincosf(TWOPI_128 * (float)m, &sa, &ca);
      float cr = ca, ci = -sa;
      float wv[16];
      *(float4*)&wv[0]  = *(const float4*)&Wrow[d0];
      *(float4*)&wv[4]  = *(const float4*)&Wrow[d0 + 4];
      *(float4*)&wv[8]  = *(const float4*)&Wrow[d0 + 8];
      *(float4*)&wv[12] = *(const float4*)&Wrow[d0 + 12];
#pragma unroll
      for (int jj = 0; jj < 16; ++jj) {
        re = fmaf(wv[jj], cr, re);
        im = fmaf(wv[jj], ci, im);
        float nc = cr * stc + ci * sts;
        ci = ci * stc - cr * sts;
        cr = nc;
      }
    }
    re *= S128; im *= S128;
  }
  int gran = (kloc & 31) >> 3, j = kloc & 7;
  int cre = (fq >> 4) * 32 + (fq & 15);
  u16 h, l;
  split2(re, h, l);
  base[(gran * 1536 + cre * 8 + j) ^ (gran << 4)] = h;
  base[6144 + ((gran * 1536 + cre * 8 + j) ^ (gran << 4))] = l;
  split2(im, h, l);
  base[(gran * 1536 + (cre + 16) * 8 + j) ^ (gran << 4)] = h;
  base[6144 + ((gran * 1536 + (cre + 16) * 8 + j) ^ (gran << 4))] = l;
}

// G (ortho irfft): out[n] = S128 * sum_k ck*(Re cos + Im*(-sin)), ck={1,2,..,1}
__global__ void k_setup_gt(void) {
  int gid = blockIdx.x * 256 + threadIdx.x;
  if (gid >= 192 * 128) return;
  int pk = gid >> 7, n = gid & 127;
  int ks = pk >> 5, w = pk & 31, gran = (w >> 3) & 3, j = w & 7;
  int part = w >> 4, fl = ks * 16 + (w & 15);
  float val = 0.f;
  if (fl <= 64) {
    float ck = (fl == 0 || fl == 64) ? 1.f : 2.f;
    int m = (fl * n) & 127;
    float sa, ca;
    sincosf(TWOPI_128 * (float)m, &sa, &ca);
    val = (part == 0 ? ca : -sa) * ck * S128;
  }
  u16 h, l;
  split2(val, h, l);
  g_gt[ks * 8192 + ((gran * 1024 + n * 8 + j) ^ (gran << 4))] = h;
  g_gt[ks * 8192 + 4096 + ((gran * 1024 + n * 8 + j) ^ (gran << 4))] = l;
}

__global__ void k_setup_fp(const float* __restrict__ b_img, const float* __restrict__ b_txt,
                           const float* __restrict__ avrf_img, const float* __restrict__ avrf_txt,
                           const float* __restrict__ avg_R, const float* __restrict__ psi) {
  int gid = blockIdx.x * 256 + threadIdx.x;
  if (gid >= 96 * 4) return;
  int k = gid >> 2, q = gid & 3;
  float* fp = g_fp + k * 8;
  if (k > 64) {
    if (q == 0) { fp[0] = 1.f; fp[1] = 0.f; fp[2] = 0.f; fp[3] = 0.f; }
    fp[4 + q] = 0.f;
    return;
  }
  if (q == 0) {
    float phi = avg_R[k] * 0.5f + psi[k];
    float s, c;
    sincosf(phi, &s, &c);
    fp[0] = c; fp[1] = s; fp[2] = avrf_img[k]; fp[3] = avrf_txt[k];
  }
  const float* b = (q < 2) ? b_img : b_txt;
  int part = q & 1;
  float acc = 0.f;
  for (int d = 0; d < 128; ++d) {
    int m = (k * d) & 127;
    float sa, ca;
    sincosf(TWOPI_128 * (float)m, &sa, &ca);
    acc = fmaf(b[d], part ? -sa : ca, acc);
  }
  fp[4 + q] = acc * S128;
}

// ---------------------------------------------------------------------------
// K1: S = A @ WF + bF  (bf16 hi/lo split MFMA), pack hi/lo u32 -> g_S.
// Grid: [0, bpm) img, [bpm, 2*bpm) txt. 256 thr = 4 waves (2x2), wave 32x96.
// NO LDS, NO BARRIERS: A fragments are per-lane 32B global loads (prefetched
// one step ahead in regs); B fragments are read directly from the L2-resident
// g_wft image (each lane's fragment is 16 contiguous bytes). Waves run fully
// independently; compiler inserts naturally-counted waitcnts.
// ---------------------------------------------------------------------------
__global__ __launch_bounds__(256) void k1_gemm(
    const float* __restrict__ Aimg, const float* __restrict__ Atxt,
    int M, int Kimg, int Ktxt, int bpm) {
  const int bid = blockIdx.x;
  const int mod = bid >= bpm;
  const int bblk = mod ? bid - bpm : bid;
  const float* A = mod ? Atxt : Aimg;
  const int K = mod ? Ktxt : Kimg;
  const u16* wft = g_wft + (mod ? (size_t)32 * 12288 : 0);
  const int row0 = bblk * 64;

  const int tid = threadIdx.x;
  const int lane = tid & 63, wv = tid >> 6;
  const int la = lane & 15, hh = lane >> 4;
  const int wr = wv >> 1, wc = wv & 1;

  // per-lane A row pointers (fragment rows), clamped
  int r0 = row0 + wr * 32 + la;      if (r0 > M - 1) r0 = M - 1;
  int r1 = row0 + wr * 32 + 16 + la; if (r1 > M - 1) r1 = M - 1;
  const float* Ar0 = A + (size_t)r0 * K + hh * 8;
  const float* Ar1 = A + (size_t)r1 * K + hh * 8;

  f32x4 acc[2][6];
#pragma unroll
  for (int rt = 0; rt < 2; ++rt)
#pragma unroll
    for (int ct = 0; ct < 6; ++ct) acc[rt][ct] = (f32x4){0.f, 0.f, 0.f, 0.f};

  // loop-invariant B fragment offsets (XOR-swizzle matches setup image)
  int boff[6];
#pragma unroll
  for (int ct = 0; ct < 6; ++ct)
    boff[ct] = (hh * 1536 + (wc * 96 + ct * 16 + la) * 8) ^ (hh << 4);

  const int nst = K / 32;

  // A(0) prefetch
  float4 av0 = *(const float4*)(Ar0);
  float4 av1 = *(const float4*)(Ar0 + 4);
  float4 av2 = *(const float4*)(Ar1);
  float4 av3 = *(const float4*)(Ar1 + 4);

  const u16* bch = wft;
  for (int s = 0; s < nst; ++s) {
    // split current A into fragments
    bf16x8 fah[2], fal[2];
    {
      u16 h8[8], l8[8];
#pragma unroll
      for (int j = 0; j < 4; ++j) {
        split2(av0[j], h8[j], l8[j]);
        split2(av1[j], h8[4 + j], l8[4 + j]);
      }
      fah[0] = *(bf16x8*)h8; fal[0] = *(bf16x8*)l8;
#pragma unroll
      for (int j = 0; j < 4; ++j) {
        split2(av2[j], h8[j], l8[j]);
        split2(av3[j], h8[4 + j], l8[4 + j]);
      }
      fah[1] = *(bf16x8*)h8; fal[1] = *(bf16x8*)l8;
    }
    // prefetch next A (issues after the split's register reads)
    if (s + 1 < nst) {
      const float* p0 = Ar0 + (s + 1) * 32;
      const float* p1 = Ar1 + (s + 1) * 32;
      av0 = *(const float4*)(p0);
      av1 = *(const float4*)(p0 + 4);
      av2 = *(const float4*)(p1);
      av3 = *(const float4*)(p1 + 4);
    }
    // B fragments straight from L2 + MFMA
#pragma unroll
    for (int ct = 0; ct < 6; ++ct) {
      const bf16x8 fbh = *(const bf16x8*)&bch[boff[ct]];
      const bf16x8 fbl = *(const bf16x8*)&bch[6144 + boff[ct]];
#pragma unroll
      for (int rt = 0; rt < 2; ++rt) {
        acc[rt][ct] = __builtin_amdgcn_mfma_f32_16x16x32_bf16(fah[rt], fbh, acc[rt][ct], 0, 0, 0);
        acc[rt][ct] = __builtin_amdgcn_mfma_f32_16x16x32_bf16(fah[rt], fbl, acc[rt][ct], 0, 0, 0);
        acc[rt][ct] = __builtin_amdgcn_mfma_f32_16x16x32_bf16(fal[rt], fbh, acc[rt][ct], 0, 0, 0);
      }
    }
    bch += 12288;
  }

  // epilogue: + bias, pack hi/lo u32, scatter to g_S in K2-fragment order
#pragma unroll
  for (int ct = 0; ct < 6; ++ct) {
    const int cg = wc * 6 + ct;
    const int fq = (cg >> 1) * 16 + la;
    const float bv = g_fp[fq * 8 + 4 + mod * 2 + (cg & 1)];
    const int ks = cg >> 1;
    const int khh = (cg & 1) * 2 + (la >> 3);
    const int j8 = la & 7;
    const size_t sbase = ((size_t)((mod * 6 + ks) * 4 + khh)) * MROWS;
#pragma unroll
    for (int rt = 0; rt < 2; ++rt) {
      const int rb = row0 + wr * 32 + rt * 16 + hh * 4;
#pragma unroll
      for (int j = 0; j < 4; ++j) {
        u16 h, l;
        split2(acc[rt][ct][j] + bv, h, l);
        g_S[(sbase + rb + j) * 8 + j8] = ((u32)h << 16) | l;
      }
    }
  }
}

// ---------------------------------------------------------------------------
// K2: mask (rot+AVRF+MSC, lane-local via shfl pairing) + iDFT via MFMA.
// 256 thr = 4 waves; wave = 16 rows x 128 out cols; Y stays in registers.
// ---------------------------------------------------------------------------
__global__ __launch_bounds__(256) void k2_idft(
    const float* __restrict__ lamw, float* __restrict__ out, int M) {
  __shared__ __align__(16) u16 Gs[8192];      // [plane2][gran4][n128][8] ^ swz
  __shared__ __align__(16) float fps[96 * 8]; // 3KB param table

  const int tid = threadIdx.x;
  const int lane = tid & 63, wv = tid >> 6;
  const int la = lane & 15, hh = lane >> 4;
  const int part = hh >> 1;                   // 0: re-lane, 1: im-lane
  const int row = blockIdx.x * 64 + wv * 16 + la;

  if (tid < 192) gll16((const char*)g_fp + tid * 16, (char*)fps + tid * 16);

  const float l0 = lamw[0], l1 = lamw[1];
  const float mx = fmaxf(l0, l1);
  const float e0 = expf(l0 - mx), e1 = expf(l1 - mx);
  const float lam0 = e0 / (e0 + e1), lam1 = e1 / (e0 + e1);

  f32x4 ai[8], at[8];
#pragma unroll
  for (int ct = 0; ct < 8; ++ct) {
    ai[ct] = (f32x4){0.f, 0.f, 0.f, 0.f};
    at[ct] = (f32x4){0.f, 0.f, 0.f, 0.f};
  }

  for (int ks = 0; ks < 6; ++ks) {
    // S loads (issue early; coalesced 512B per 16-lane quarter)
    const u32* si = &g_S[((size_t)((0 + ks) * 4 + hh) * MROWS + row) * 8];
    const u32* st = &g_S[((size_t)((24 + ks * 4) + hh) * MROWS + row) * 8];
    uint4 vi0 = *(const uint4*)si, vi1 = *(const uint4*)(si + 4);
    uint4 vt0 = *(const uint4*)st, vt1 = *(const uint4*)(st + 4);

    __syncthreads();                          // prev iter's G reads done
#pragma unroll
    for (int i = 0; i < 4; ++i)
      gll16((const char*)(g_gt + ks * 8192) + i * 4096 + tid * 16,
            (char*)Gs + i * 4096 + tid * 16);
    __syncthreads();                          // G (+fps) visible

    u32 vs_i[8], vs_t[8];
    *(uint4*)&vs_i[0] = vi0; *(uint4*)&vs_i[4] = vi1;
    *(uint4*)&vs_t[0] = vt0; *(uint4*)&vs_t[4] = vt1;

    const int fq0 = ks * 16 + (hh & 1) * 8;
    u16 yih[8], yil[8], yth[8], ytl[8];
#pragma unroll
    for (int j = 0; j < 8; ++j) {
      const f32x4 fpv = *(const f32x4*)&fps[(fq0 + j) * 8];  // rc, rs, avI, avT
      const float o_i = __uint_as_float(vs_i[j] & 0xFFFF0000u) + __uint_as_float(vs_i[j] << 16);
      const float o_t = __uint_as_float(vs_t[j] & 0xFFFF0000u) + __uint_as_float(vs_t[j] << 16);
      const float p_i = __shfl_xor(o_i, 32);
      const float p_t = __shfl_xor(o_t, 32);
      const float Sre_i = part ? p_i : o_i;
      const float Sim_i = part ? o_i : p_i;
      const float Sre_t = part ? p_t : o_t;
      const float Sim_t = part ? o_t : p_t;
      const float rc = fpv[0], rs = fpv[1];
      const float Air = Sre_i * rc + Sim_i * rs, Aii = Sim_i * rc - Sre_i * rs;  // * e^{-i phi}
      const float Atr = Sre_t * rc - Sim_t * rs, Ati = Sim_t * rc + Sre_t * rs;  // * conj
      const float cre = Air * Atr + Aii * Ati, cim = Aii * Atr - Air * Ati;
      const float pa = Air * Air + Aii * Aii, pb = Atr * Atr + Ati * Ati;
      const float msc = (cre * cre + cim * cim) / (pa * pb + 1e-8f);
      const float mi = lam0 * fpv[2] + lam1 * msc;
      const float mt = lam0 * fpv[3] + lam1 * msc;
      const float yi = (part ? Aii : Air) * mi;
      const float yt = (part ? Ati : Atr) * mt;
      split2(yi, yih[j], yil[j]);
      split2(yt, yth[j], ytl[j]);
    }
    const bf16x8 fih = *(bf16x8*)yih, fil = *(bf16x8*)yil;
    const bf16x8 fth = *(bf16x8*)yth, ftl = *(bf16x8*)ytl;
#pragma unroll
    for (int ct = 0; ct < 8; ++ct) {
      const int goff = (hh * 1024 + (ct * 16 + la) * 8) ^ (hh << 4);
      const bf16x8 gh = *(const bf16x8*)&Gs[goff];
      const bf16x8 gl = *(const bf16x8*)&Gs[4096 + goff];
      ai[ct] = __builtin_amdgcn_mfma_f32_16x16x32_bf16(fih, gh, ai[ct], 0, 0, 0);
      ai[ct] = __builtin_amdgcn_mfma_f32_16x16x32_bf16(fih, gl, ai[ct], 0, 0, 0);
      ai[ct] = __builtin_amdgcn_mfma_f32_16x16x32_bf16(fil, gh, ai[ct], 0, 0, 0);
      at[ct] = __builtin_amdgcn_mfma_f32_16x16x32_bf16(fth, gh, at[ct], 0, 0, 0);
      at[ct] = __builtin_amdgcn_mfma_f32_16x16x32_bf16(fth, gl, at[ct], 0, 0, 0);
      at[ct] = __builtin_amdgcn_mfma_f32_16x16x32_bf16(ftl, gh, at[ct], 0, 0, 0);
    }
  }

  float* oimg = out;
  float* otxt = out + (size_t)M * 128;
#pragma unroll
  for (int q = 0; q < 4; ++q) {
    const int orow = blockIdx.x * 64 + wv * 16 + hh * 4 + q;
    if (orow < M) {
#pragma unroll
      for (int ct = 0; ct < 8; ++ct) {
        oimg[(size_t)orow * 128 + ct * 16 + la] = ai[ct][q];
        otxt[(size_t)orow * 128 + ct * 16 + la] = at[ct][q];
      }
    }
  }
}

extern "C" void kernel_launch(void* const* d_in, const int* in_sizes, int n_in,
                              void* d_out, int out_size, void* d_ws, size_t ws_size,
                              hipStream_t stream) {
  const float* image_table = (const float*)d_in[2];
  const float* text_table  = (const float*)d_in[3];
  const float* W_img = (const float*)d_in[4];
  const float* b_img = (const float*)d_in[5];
  const float* W_txt = (const float*)d_in[6];
  const float* b_txt = (const float*)d_in[7];
  const float* avrf_img = (const float*)d_in[8];
  const float* avrf_txt = (const float*)d_in[9];
  const float* avg_R = (const float*)d_in[10];
  const float* psi = (const float*)d_in[11];
  const float* lamw = (const float*)d_in[12];

  const int M = in_sizes[0] / 128;        // 30000
  const int K_img = in_sizes[4] / 128;    // 1024
  const int K_txt = in_sizes[6] / 128;    // 768

  const int wft_threads = (K_img + K_txt) * 96;
  k_setup_wft<<<(wft_threads + 255) / 256, 256, 0, stream>>>(W_img, W_txt, K_img, K_txt);
  k_setup_gt<<<(192 * 128 + 255) / 256, 256, 0, stream>>>();
  k_setup_fp<<<2, 256, 0, stream>>>(b_img, b_txt, avrf_img, avrf_txt, avg_R, psi);

  const int bpm = (M + 63) / 64;          // 469
  k1_gemm<<<2 * bpm, 256, 0, stream>>>(image_table, text_table, M, K_img, K_txt, bpm);
  k2_idft<<<bpm, 256, 0, stream>>>(lamw, (float*)d_out, M);
}

// Round 8
// 187.083 us; speedup vs baseline: 1.2473x; 1.2473x over previous
//
#include <hip/hip_runtime.h>
#include <math.h>

typedef __bf16 bf16x8 __attribute__((ext_vector_type(8)));
typedef float f32x4 __attribute__((ext_vector_type(4)));
typedef unsigned short u16;
typedef unsigned int u32;

#define S128 0.08838834764831845f       // 1/sqrt(128)
#define TWOPI_128 0.04908738521234052f  // 2*pi/128
#define MROWS 30016                     // 469*64 (padded row capacity)

// ---------------------------------------------------------------------------
// Device-global precomputed operands.
// g_wft: per (mod, ks) chunk of 12288 u16 = [plane2][gran4][col192][8],
//        intra-plane offsets XOR-swizzled with (gran<<4) (u16 units).
// g_gt : per ks chunk of 8192 u16 = [plane2][gran4][n128][8], same swz.
// g_fp : per freq k (0..95): {rotc, rots, avrfI, avrfT, bIre, bIim, bTre, bTim}
// g_S  : spectra hi/lo packed u32, layout [mod][ks6][khh4][row MROWS][8]
// ---------------------------------------------------------------------------
__device__ __align__(16) u16 g_wft[56 * 12288];
__device__ __align__(16) u16 g_gt[6 * 8192];
__device__ __align__(16) float g_fp[96 * 8];
__device__ __align__(16) u32 g_S[(size_t)2 * 6 * 4 * MROWS * 8];

__device__ __forceinline__ void split2(float v, u16& h, u16& l) {
  unsigned u = __float_as_uint(v);
  h = (u16)(u >> 16);
  float hf = __uint_as_float(u & 0xFFFF0000u);
  float lo = v - hf;
  unsigned ul = __float_as_uint(lo);
  l = (u16)((ul + 0x7FFFu + ((ul >> 16) & 1u)) >> 16);
}

__device__ __forceinline__ void gll16(const void* gsrc, void* ldst) {
  __builtin_amdgcn_global_load_lds(
      (const __attribute__((address_space(1))) unsigned int*)gsrc,
      (__attribute__((address_space(3))) unsigned int*)ldst, 16, 0, 0);
}

// ---------------------------------------------------------------------------
// Setup: WF = W @ F (ortho rfft matrix), bf16 hi/lo, k-granule-major chunks,
// granule XOR-swizzle baked into the global image.
// ---------------------------------------------------------------------------
__global__ void k_setup_wft(const float* __restrict__ Wimg,
                            const float* __restrict__ Wtxt, int Kimg, int Ktxt) {
  int gid = blockIdx.x * 256 + threadIdx.x;
  int imgn = Kimg * 96;
  if (gid >= imgn + Ktxt * 96) return;
  const float* Wrow;
  u16* base;
  int kloc, fq;
  if (gid < imgn) {
    kloc = gid / 96; fq = gid % 96;
    Wrow = Wimg + (size_t)kloc * 128;
    base = g_wft + (size_t)(kloc >> 5) * 12288;
  } else {
    int l = gid - imgn;
    kloc = l / 96; fq = l % 96;
    Wrow = Wtxt + (size_t)kloc * 128;
    base = g_wft + (size_t)(32 + (kloc >> 5)) * 12288;
  }
  float re = 0.f, im = 0.f;
  if (fq <= 64) {
    float sts, stc;
    sincosf(TWOPI_128 * (float)fq, &sts, &stc);   // step e^{-ia} = (stc, -sts)
    for (int d0 = 0; d0 < 128; d0 += 16) {
      int m = (fq * d0) & 127;
      float sa, ca;
      sincosf(TWOPI_128 * (float)m, &sa, &ca);
      float cr = ca, ci = -sa;
      float wv[16];
      *(float4*)&wv[0]  = *(const float4*)&Wrow[d0];
      *(float4*)&wv[4]  = *(const float4*)&Wrow[d0 + 4];
      *(float4*)&wv[8]  = *(const float4*)&Wrow[d0 + 8];
      *(float4*)&wv[12] = *(const float4*)&Wrow[d0 + 12];
#pragma unroll
      for (int jj = 0; jj < 16; ++jj) {
        re = fmaf(wv[jj], cr, re);
        im = fmaf(wv[jj], ci, im);
        float nc = cr * stc + ci * sts;
        ci = ci * stc - cr * sts;
        cr = nc;
      }
    }
    re *= S128; im *= S128;
  }
  int gran = (kloc & 31) >> 3, j = kloc & 7;
  int cre = (fq >> 4) * 32 + (fq & 15);
  u16 h, l;
  split2(re, h, l);
  base[(gran * 1536 + cre * 8 + j) ^ (gran << 4)] = h;
  base[6144 + ((gran * 1536 + cre * 8 + j) ^ (gran << 4))] = l;
  split2(im, h, l);
  base[(gran * 1536 + (cre + 16) * 8 + j) ^ (gran << 4)] = h;
  base[6144 + ((gran * 1536 + (cre + 16) * 8 + j) ^ (gran << 4))] = l;
}

// G (ortho irfft): out[n] = S128 * sum_k ck*(Re cos + Im*(-sin)), ck={1,2,..,1}
__global__ void k_setup_gt(void) {
  int gid = blockIdx.x * 256 + threadIdx.x;
  if (gid >= 192 * 128) return;
  int pk = gid >> 7, n = gid & 127;
  int ks = pk >> 5, w = pk & 31, gran = (w >> 3) & 3, j = w & 7;
  int part = w >> 4, fl = ks * 16 + (w & 15);
  float val = 0.f;
  if (fl <= 64) {
    float ck = (fl == 0 || fl == 64) ? 1.f : 2.f;
    int m = (fl * n) & 127;
    float sa, ca;
    sincosf(TWOPI_128 * (float)m, &sa, &ca);
    val = (part == 0 ? ca : -sa) * ck * S128;
  }
  u16 h, l;
  split2(val, h, l);
  g_gt[ks * 8192 + ((gran * 1024 + n * 8 + j) ^ (gran << 4))] = h;
  g_gt[ks * 8192 + 4096 + ((gran * 1024 + n * 8 + j) ^ (gran << 4))] = l;
}

__global__ void k_setup_fp(const float* __restrict__ b_img, const float* __restrict__ b_txt,
                           const float* __restrict__ avrf_img, const float* __restrict__ avrf_txt,
                           const float* __restrict__ avg_R, const float* __restrict__ psi) {
  int gid = blockIdx.x * 256 + threadIdx.x;
  if (gid >= 96 * 4) return;
  int k = gid >> 2, q = gid & 3;
  float* fp = g_fp + k * 8;
  if (k > 64) {
    if (q == 0) { fp[0] = 1.f; fp[1] = 0.f; fp[2] = 0.f; fp[3] = 0.f; }
    fp[4 + q] = 0.f;
    return;
  }
  if (q == 0) {
    float phi = avg_R[k] * 0.5f + psi[k];
    float s, c;
    sincosf(phi, &s, &c);
    fp[0] = c; fp[1] = s; fp[2] = avrf_img[k]; fp[3] = avrf_txt[k];
  }
  const float* b = (q < 2) ? b_img : b_txt;
  int part = q & 1;
  float acc = 0.f;
  for (int d = 0; d < 128; ++d) {
    int m = (k * d) & 127;
    float sa, ca;
    sincosf(TWOPI_128 * (float)m, &sa, &ca);
    acc = fmaf(b[d], part ? -sa : ca, acc);
  }
  fp[4 + q] = acc * S128;
}

// ---------------------------------------------------------------------------
// K1: S = A @ WF + bF  (bf16 hi/lo split MFMA), pack hi/lo u32 -> g_S.
// Grid: [0, bpm) img, [bpm, 2*bpm) txt. 256 thr = 4 waves (2x2), wave 32x96.
// Hybrid staging, ONE barrier per K-step:
//   A: per-lane 32B global loads -> regs -> split -> MFMA fragments (no LDS).
//   B: double-buffered LDS via global_load_lds; DMA for s+1 issued right
//      after the barrier, drained by the compiler's vmcnt(0) before the NEXT
//      barrier -> a full LDS-read+MFMA phase of overlap.
// LDS = 48KB -> 3 blocks/CU.
// ---------------------------------------------------------------------------
__global__ __launch_bounds__(256) void k1_gemm(
    const float* __restrict__ Aimg, const float* __restrict__ Atxt,
    int M, int Kimg, int Ktxt, int bpm) {
  __shared__ __align__(16) u16 Bsm[2 * 12288];  // dbuf x [plane2][gran4][col192][8] ^ swz

  const int bid = blockIdx.x;
  const int mod = bid >= bpm;
  const int bblk = mod ? bid - bpm : bid;
  const float* A = mod ? Atxt : Aimg;
  const int K = mod ? Ktxt : Kimg;
  const u16* wft = g_wft + (mod ? (size_t)32 * 12288 : 0);
  const int row0 = bblk * 64;

  const int tid = threadIdx.x;
  const int lane = tid & 63, wv = tid >> 6;
  const int la = lane & 15, hh = lane >> 4;
  const int wr = wv >> 1, wc = wv & 1;

  // per-lane A row pointers (fragment rows), clamped
  int r0 = row0 + wr * 32 + la;      if (r0 > M - 1) r0 = M - 1;
  int r1 = row0 + wr * 32 + 16 + la; if (r1 > M - 1) r1 = M - 1;
  const float* Ar0 = A + (size_t)r0 * K + hh * 8;
  const float* Ar1 = A + (size_t)r1 * K + hh * 8;

  f32x4 acc[2][6];
#pragma unroll
  for (int rt = 0; rt < 2; ++rt)
#pragma unroll
    for (int ct = 0; ct < 6; ++ct) acc[rt][ct] = (f32x4){0.f, 0.f, 0.f, 0.f};

  // loop-invariant B fragment offsets (XOR-swizzle matches setup image)
  int boff[6];
#pragma unroll
  for (int ct = 0; ct < 6; ++ct)
    boff[ct] = (hh * 1536 + (wc * 96 + ct * 16 + la) * 8) ^ (hh << 4);

  const int nst = K / 32;

  auto stageB = [&](int s, int buf) {
    const u16* src = wft + (size_t)s * 12288;
    char* dst = (char*)Bsm + buf * 24576;
#pragma unroll
    for (int i = 0; i < 6; ++i)
      gll16(src + i * 2048 + tid * 8, dst + i * 4096 + tid * 16);
  };

  // prologue: B(0) DMA + A(0) per-lane loads
  stageB(0, 0);
  float4 av0 = *(const float4*)(Ar0);
  float4 av1 = *(const float4*)(Ar0 + 4);
  float4 av2 = *(const float4*)(Ar1);
  float4 av3 = *(const float4*)(Ar1 + 4);

  for (int s = 0; s < nst; ++s) {
    const int cur = s & 1;
    __syncthreads();               // B(s) DMA landed; buf[cur^1] readers done

    if (s + 1 < nst) stageB(s + 1, cur ^ 1);   // overlaps everything below

    // split current A into fragments (frees av regs)
    bf16x8 fah[2], fal[2];
    {
      u16 h8[8], l8[8];
#pragma unroll
      for (int j = 0; j < 4; ++j) {
        split2(av0[j], h8[j], l8[j]);
        split2(av1[j], h8[4 + j], l8[4 + j]);
      }
      fah[0] = *(bf16x8*)h8; fal[0] = *(bf16x8*)l8;
#pragma unroll
      for (int j = 0; j < 4; ++j) {
        split2(av2[j], h8[j], l8[j]);
        split2(av3[j], h8[4 + j], l8[4 + j]);
      }
      fah[1] = *(bf16x8*)h8; fal[1] = *(bf16x8*)l8;
    }
    // prefetch next A (per-lane, coalesces to 128B segments across hh)
    if (s + 1 < nst) {
      const float* p0 = Ar0 + (s + 1) * 32;
      const float* p1 = Ar1 + (s + 1) * 32;
      av0 = *(const float4*)(p0);
      av1 = *(const float4*)(p0 + 4);
      av2 = *(const float4*)(p1);
      av3 = *(const float4*)(p1 + 4);
    }

    // B fragment reads (conflict-free, swizzled) + MFMA
    const u16* bb0 = Bsm + cur * 12288;
#pragma unroll
    for (int ct = 0; ct < 6; ++ct) {
      const bf16x8 fbh = *(const bf16x8*)&bb0[boff[ct]];
      const bf16x8 fbl = *(const bf16x8*)&bb0[6144 + boff[ct]];
#pragma unroll
      for (int rt = 0; rt < 2; ++rt) {
        acc[rt][ct] = __builtin_amdgcn_mfma_f32_16x16x32_bf16(fah[rt], fbh, acc[rt][ct], 0, 0, 0);
        acc[rt][ct] = __builtin_amdgcn_mfma_f32_16x16x32_bf16(fah[rt], fbl, acc[rt][ct], 0, 0, 0);
        acc[rt][ct] = __builtin_amdgcn_mfma_f32_16x16x32_bf16(fal[rt], fbh, acc[rt][ct], 0, 0, 0);
      }
    }
  }

  // epilogue: + bias, pack hi/lo u32, scatter to g_S in K2-fragment order
#pragma unroll
  for (int ct = 0; ct < 6; ++ct) {
    const int cg = wc * 6 + ct;
    const int fq = (cg >> 1) * 16 + la;
    const float bv = g_fp[fq * 8 + 4 + mod * 2 + (cg & 1)];
    const int ks = cg >> 1;
    const int khh = (cg & 1) * 2 + (la >> 3);
    const int j8 = la & 7;
    const size_t sbase = ((size_t)((mod * 6 + ks) * 4 + khh)) * MROWS;
#pragma unroll
    for (int rt = 0; rt < 2; ++rt) {
      const int rb = row0 + wr * 32 + rt * 16 + hh * 4;
#pragma unroll
      for (int j = 0; j < 4; ++j) {
        u16 h, l;
        split2(acc[rt][ct][j] + bv, h, l);
        g_S[(sbase + rb + j) * 8 + j8] = ((u32)h << 16) | l;
      }
    }
  }
}

// ---------------------------------------------------------------------------
// K2: mask (rot+AVRF+MSC, lane-local via shfl pairing) + iDFT via MFMA.
// 256 thr = 4 waves; wave = 16 rows x 128 out cols; Y stays in registers.
// ---------------------------------------------------------------------------
__global__ __launch_bounds__(256) void k2_idft(
    const float* __restrict__ lamw, float* __restrict__ out, int M) {
  __shared__ __align__(16) u16 Gs[8192];      // [plane2][gran4][n128][8] ^ swz
  __shared__ __align__(16) float fps[96 * 8]; // 3KB param table

  const int tid = threadIdx.x;
  const int lane = tid & 63, wv = tid >> 6;
  const int la = lane & 15, hh = lane >> 4;
  const int part = hh >> 1;                   // 0: re-lane, 1: im-lane
  const int row = blockIdx.x * 64 + wv * 16 + la;

  if (tid < 192) gll16((const char*)g_fp + tid * 16, (char*)fps + tid * 16);

  const float l0 = lamw[0], l1 = lamw[1];
  const float mx = fmaxf(l0, l1);
  const float e0 = expf(l0 - mx), e1 = expf(l1 - mx);
  const float lam0 = e0 / (e0 + e1), lam1 = e1 / (e0 + e1);

  f32x4 ai[8], at[8];
#pragma unroll
  for (int ct = 0; ct < 8; ++ct) {
    ai[ct] = (f32x4){0.f, 0.f, 0.f, 0.f};
    at[ct] = (f32x4){0.f, 0.f, 0.f, 0.f};
  }

  for (int ks = 0; ks < 6; ++ks) {
    // S loads (issue early; coalesced 512B per 16-lane quarter)
    const u32* si = &g_S[((size_t)((0 + ks) * 4 + hh) * MROWS + row) * 8];
    const u32* st = &g_S[((size_t)((24 + ks * 4) + hh) * MROWS + row) * 8];
    uint4 vi0 = *(const uint4*)si, vi1 = *(const uint4*)(si + 4);
    uint4 vt0 = *(const uint4*)st, vt1 = *(const uint4*)(st + 4);

    __syncthreads();                          // prev iter's G reads done
#pragma unroll
    for (int i = 0; i < 4; ++i)
      gll16((const char*)(g_gt + ks * 8192) + i * 4096 + tid * 16,
            (char*)Gs + i * 4096 + tid * 16);
    __syncthreads();                          // G (+fps) visible

    u32 vs_i[8], vs_t[8];
    *(uint4*)&vs_i[0] = vi0; *(uint4*)&vs_i[4] = vi1;
    *(uint4*)&vs_t[0] = vt0; *(uint4*)&vs_t[4] = vt1;

    const int fq0 = ks * 16 + (hh & 1) * 8;
    u16 yih[8], yil[8], yth[8], ytl[8];
#pragma unroll
    for (int j = 0; j < 8; ++j) {
      const f32x4 fpv = *(const f32x4*)&fps[(fq0 + j) * 8];  // rc, rs, avI, avT
      const float o_i = __uint_as_float(vs_i[j] & 0xFFFF0000u) + __uint_as_float(vs_i[j] << 16);
      const float o_t = __uint_as_float(vs_t[j] & 0xFFFF0000u) + __uint_as_float(vs_t[j] << 16);
      const float p_i = __shfl_xor(o_i, 32);
      const float p_t = __shfl_xor(o_t, 32);
      const float Sre_i = part ? p_i : o_i;
      const float Sim_i = part ? o_i : p_i;
      const float Sre_t = part ? p_t : o_t;
      const float Sim_t = part ? o_t : p_t;
      const float rc = fpv[0], rs = fpv[1];
      const float Air = Sre_i * rc + Sim_i * rs, Aii = Sim_i * rc - Sre_i * rs;  // * e^{-i phi}
      const float Atr = Sre_t * rc - Sim_t * rs, Ati = Sim_t * rc + Sre_t * rs;  // * conj
      const float cre = Air * Atr + Aii * Ati, cim = Aii * Atr - Air * Ati;
      const float pa = Air * Air + Aii * Aii, pb = Atr * Atr + Ati * Ati;
      const float msc = (cre * cre + cim * cim) / (pa * pb + 1e-8f);
      const float mi = lam0 * fpv[2] + lam1 * msc;
      const float mt = lam0 * fpv[3] + lam1 * msc;
      const float yi = (part ? Aii : Air) * mi;
      const float yt = (part ? Ati : Atr) * mt;
      split2(yi, yih[j], yil[j]);
      split2(yt, yth[j], ytl[j]);
    }
    const bf16x8 fih = *(bf16x8*)yih, fil = *(bf16x8*)yil;
    const bf16x8 fth = *(bf16x8*)yth, ftl = *(bf16x8*)ytl;
#pragma unroll
    for (int ct = 0; ct < 8; ++ct) {
      const int goff = (hh * 1024 + (ct * 16 + la) * 8) ^ (hh << 4);
      const bf16x8 gh = *(const bf16x8*)&Gs[goff];
      const bf16x8 gl = *(const bf16x8*)&Gs[4096 + goff];
      ai[ct] = __builtin_amdgcn_mfma_f32_16x16x32_bf16(fih, gh, ai[ct], 0, 0, 0);
      ai[ct] = __builtin_amdgcn_mfma_f32_16x16x32_bf16(fih, gl, ai[ct], 0, 0, 0);
      ai[ct] = __builtin_amdgcn_mfma_f32_16x16x32_bf16(fil, gh, ai[ct], 0, 0, 0);
      at[ct] = __builtin_amdgcn_mfma_f32_16x16x32_bf16(fth, gh, at[ct], 0, 0, 0);
      at[ct] = __builtin_amdgcn_mfma_f32_16x16x32_bf16(fth, gl, at[ct], 0, 0, 0);
      at[ct] = __builtin_amdgcn_mfma_f32_16x16x32_bf16(ftl, gh, at[ct], 0, 0, 0);
    }
  }

  float* oimg = out;
  float* otxt = out + (size_t)M * 128;
#pragma unroll
  for (int q = 0; q < 4; ++q) {
    const int orow = blockIdx.x * 64 + wv * 16 + hh * 4 + q;
    if (orow < M) {
#pragma unroll
      for (int ct = 0; ct < 8; ++ct) {
        oimg[(size_t)orow * 128 + ct * 16 + la] = ai[ct][q];
        otxt[(size_t)orow * 128 + ct * 16 + la] = at[ct][q];
      }
    }
  }
}

extern "C" void kernel_launch(void* const* d_in, const int* in_sizes, int n_in,
                              void* d_out, int out_size, void* d_ws, size_t ws_size,
                              hipStream_t stream) {
  const float* image_table = (const float*)d_in[2];
  const float* text_table  = (const float*)d_in[3];
  const float* W_img = (const float*)d_in[4];
  const float* b_img = (const float*)d_in[5];
  const float* W_txt = (const float*)d_in[6];
  const float* b_txt = (const float*)d_in[7];
  const float* avrf_img = (const float*)d_in[8];
  const float* avrf_txt = (const float*)d_in[9];
  const float* avg_R = (const float*)d_in[10];
  const float* psi = (const float*)d_in[11];
  const float* lamw = (const float*)d_in[12];

  const int M = in_sizes[0] / 128;        // 30000
  const int K_img = in_sizes[4] / 128;    // 1024
  const int K_txt = in_sizes[6] / 128;    // 768

  const int wft_threads = (K_img + K_txt) * 96;
  k_setup_wft<<<(wft_threads + 255) / 256, 256, 0, stream>>>(W_img, W_txt, K_img, K_txt);
  k_setup_gt<<<(192 * 128 + 255) / 256, 256, 0, stream>>>();
  k_setup_fp<<<2, 256, 0, stream>>>(b_img, b_txt, avrf_img, avrf_txt, avg_R, psi);

  const int bpm = (M + 63) / 64;          // 469
  k1_gemm<<<2 * bpm, 256, 0, stream>>>(image_table, text_table, M, K_img, K_txt, bpm);
  k2_idft<<<bpm, 256, 0, stream>>>(lamw, (float*)d_out, M);
}

// Round 9
// 177.552 us; speedup vs baseline: 1.3142x; 1.0537x over previous
//
#include <hip/hip_runtime.h>
#include <math.h>

typedef __bf16 bf16x8 __attribute__((ext_vector_type(8)));
typedef float f32x4 __attribute__((ext_vector_type(4)));
typedef unsigned short u16;
typedef unsigned int u32;

#define S128 0.08838834764831845f       // 1/sqrt(128)
#define TWOPI_128 0.04908738521234052f  // 2*pi/128
#define MROWS 30016                     // 469*64 (padded row capacity)

#define WAITVM10() asm volatile("s_waitcnt vmcnt(10)" ::: "memory")
#define WAITVM0()  asm volatile("s_waitcnt vmcnt(0)" ::: "memory")
#define SCHEDB()   __builtin_amdgcn_sched_barrier(0)

// ---------------------------------------------------------------------------
// Device-global precomputed operands.
// g_wft: per (mod, ks) chunk of 12288 u16 = [plane2][gran4][col192][8],
//        intra-plane offsets XOR-swizzled with (gran<<4) (u16 units).
// g_gt : per ks chunk of 8192 u16 = [plane2][gran4][n128][8], same swz.
// g_fp : per freq k (0..95): {rotc, rots, avrfI, avrfT, bIre, bIim, bTre, bTim}
// g_S  : spectra hi/lo packed u32, layout [mod][ks6][khh4][row MROWS][8]
// ---------------------------------------------------------------------------
__device__ __align__(16) u16 g_wft[56 * 12288];
__device__ __align__(16) u16 g_gt[6 * 8192];
__device__ __align__(16) float g_fp[96 * 8];
__device__ __align__(16) u32 g_S[(size_t)2 * 6 * 4 * MROWS * 8];

__device__ __forceinline__ void split2(float v, u16& h, u16& l) {
  unsigned u = __float_as_uint(v);
  h = (u16)(u >> 16);
  float hf = __uint_as_float(u & 0xFFFF0000u);
  float lo = v - hf;
  unsigned ul = __float_as_uint(lo);
  l = (u16)((ul + 0x7FFFu + ((ul >> 16) & 1u)) >> 16);
}

__device__ __forceinline__ void gll16(const void* gsrc, void* ldst) {
  __builtin_amdgcn_global_load_lds(
      (const __attribute__((address_space(1))) unsigned int*)gsrc,
      (__attribute__((address_space(3))) unsigned int*)ldst, 16, 0, 0);
}

// ---------------------------------------------------------------------------
// Setup: WF = W @ F (ortho rfft matrix), bf16 hi/lo, k-granule-major chunks,
// granule XOR-swizzle baked into the global image.
// ---------------------------------------------------------------------------
__global__ void k_setup_wft(const float* __restrict__ Wimg,
                            const float* __restrict__ Wtxt, int Kimg, int Ktxt) {
  int gid = blockIdx.x * 256 + threadIdx.x;
  int imgn = Kimg * 96;
  if (gid >= imgn + Ktxt * 96) return;
  const float* Wrow;
  u16* base;
  int kloc, fq;
  if (gid < imgn) {
    kloc = gid / 96; fq = gid % 96;
    Wrow = Wimg + (size_t)kloc * 128;
    base = g_wft + (size_t)(kloc >> 5) * 12288;
  } else {
    int l = gid - imgn;
    kloc = l / 96; fq = l % 96;
    Wrow = Wtxt + (size_t)kloc * 128;
    base = g_wft + (size_t)(32 + (kloc >> 5)) * 12288;
  }
  float re = 0.f, im = 0.f;
  if (fq <= 64) {
    float sts, stc;
    sincosf(TWOPI_128 * (float)fq, &sts, &stc);   // step e^{-ia} = (stc, -sts)
    for (int d0 = 0; d0 < 128; d0 += 16) {
      int m = (fq * d0) & 127;
      float sa, ca;
      sincosf(TWOPI_128 * (float)m, &sa, &ca);
      float cr = ca, ci = -sa;
      float wv[16];
      *(float4*)&wv[0]  = *(const float4*)&Wrow[d0];
      *(float4*)&wv[4]  = *(const float4*)&Wrow[d0 + 4];
      *(float4*)&wv[8]  = *(const float4*)&Wrow[d0 + 8];
      *(float4*)&wv[12] = *(const float4*)&Wrow[d0 + 12];
#pragma unroll
      for (int jj = 0; jj < 16; ++jj) {
        re = fmaf(wv[jj], cr, re);
        im = fmaf(wv[jj], ci, im);
        float nc = cr * stc + ci * sts;
        ci = ci * stc - cr * sts;
        cr = nc;
      }
    }
    re *= S128; im *= S128;
  }
  int gran = (kloc & 31) >> 3, j = kloc & 7;
  int cre = (fq >> 4) * 32 + (fq & 15);
  u16 h, l;
  split2(re, h, l);
  base[(gran * 1536 + cre * 8 + j) ^ (gran << 4)] = h;
  base[6144 + ((gran * 1536 + cre * 8 + j) ^ (gran << 4))] = l;
  split2(im, h, l);
  base[(gran * 1536 + (cre + 16) * 8 + j) ^ (gran << 4)] = h;
  base[6144 + ((gran * 1536 + (cre + 16) * 8 + j) ^ (gran << 4))] = l;
}

// G (ortho irfft): out[n] = S128 * sum_k ck*(Re cos + Im*(-sin)), ck={1,2,..,1}
__global__ void k_setup_gt(void) {
  int gid = blockIdx.x * 256 + threadIdx.x;
  if (gid >= 192 * 128) return;
  int pk = gid >> 7, n = gid & 127;
  int ks = pk >> 5, w = pk & 31, gran = (w >> 3) & 3, j = w & 7;
  int part = w >> 4, fl = ks * 16 + (w & 15);
  float val = 0.f;
  if (fl <= 64) {
    float ck = (fl == 0 || fl == 64) ? 1.f : 2.f;
    int m = (fl * n) & 127;
    float sa, ca;
    sincosf(TWOPI_128 * (float)m, &sa, &ca);
    val = (part == 0 ? ca : -sa) * ck * S128;
  }
  u16 h, l;
  split2(val, h, l);
  g_gt[ks * 8192 + ((gran * 1024 + n * 8 + j) ^ (gran << 4))] = h;
  g_gt[ks * 8192 + 4096 + ((gran * 1024 + n * 8 + j) ^ (gran << 4))] = l;
}

__global__ void k_setup_fp(const float* __restrict__ b_img, const float* __restrict__ b_txt,
                           const float* __restrict__ avrf_img, const float* __restrict__ avrf_txt,
                           const float* __restrict__ avg_R, const float* __restrict__ psi) {
  int gid = blockIdx.x * 256 + threadIdx.x;
  if (gid >= 96 * 4) return;
  int k = gid >> 2, q = gid & 3;
  float* fp = g_fp + k * 8;
  if (k > 64) {
    if (q == 0) { fp[0] = 1.f; fp[1] = 0.f; fp[2] = 0.f; fp[3] = 0.f; }
    fp[4 + q] = 0.f;
    return;
  }
  if (q == 0) {
    float phi = avg_R[k] * 0.5f + psi[k];
    float s, c;
    sincosf(phi, &s, &c);
    fp[0] = c; fp[1] = s; fp[2] = avrf_img[k]; fp[3] = avrf_txt[k];
  }
  const float* b = (q < 2) ? b_img : b_txt;
  int part = q & 1;
  float acc = 0.f;
  for (int d = 0; d < 128; ++d) {
    int m = (k * d) & 127;
    float sa, ca;
    sincosf(TWOPI_128 * (float)m, &sa, &ca);
    acc = fmaf(b[d], part ? -sa : ca, acc);
  }
  fp[4 + q] = acc * S128;
}

// ---------------------------------------------------------------------------
// K1: S = A @ WF + bF  (bf16 hi/lo split MFMA), pack hi/lo u32 -> g_S.
// Grid: [0, bpm) img, [bpm, 2*bpm) txt. 256 thr = 4 waves (2x2), wave 32x96.
// T3/T4 pipeline, ONE raw s_barrier per step, COUNTED vmcnt:
//   batch(s) = [4 per-lane A loads -> regs] + [6 gll B -> LDS buf s%3],
//   issued during step s-2.  Step-s top: s_waitcnt vmcnt(10) (batch(s+1)
//   stays in flight across the barrier) -> s_barrier -> split A(s) ->
//   issue batch(s+2) -> ds_read B(s) + 36 MFMA.
// Every load gets ~2 full steps to land instead of a fraction of one.
// LDS = 72KB (3 x 24KB B buffers) -> 2 blocks/CU.
// ---------------------------------------------------------------------------
__global__ __launch_bounds__(256) void k1_gemm(
    const float* __restrict__ Aimg, const float* __restrict__ Atxt,
    int M, int Kimg, int Ktxt, int bpm) {
  __shared__ __align__(16) u16 Bsm[3 * 12288];  // 3-buf x [plane2][gran4][col192][8] ^ swz

  const int bid = blockIdx.x;
  const int mod = bid >= bpm;
  const int bblk = mod ? bid - bpm : bid;
  const float* A = mod ? Atxt : Aimg;
  const int K = mod ? Ktxt : Kimg;
  const u16* wft = g_wft + (mod ? (size_t)32 * 12288 : 0);
  const int row0 = bblk * 64;

  const int tid = threadIdx.x;
  const int lane = tid & 63, wv = tid >> 6;
  const int la = lane & 15, hh = lane >> 4;
  const int wr = wv >> 1, wc = wv & 1;

  // per-lane A row pointers (fragment rows), clamped
  int r0 = row0 + wr * 32 + la;      if (r0 > M - 1) r0 = M - 1;
  int r1 = row0 + wr * 32 + 16 + la; if (r1 > M - 1) r1 = M - 1;
  const float* Ar0 = A + (size_t)r0 * K + hh * 8;
  const float* Ar1 = A + (size_t)r1 * K + hh * 8;

  f32x4 acc[2][6];
#pragma unroll
  for (int rt = 0; rt < 2; ++rt)
#pragma unroll
    for (int ct = 0; ct < 6; ++ct) acc[rt][ct] = (f32x4){0.f, 0.f, 0.f, 0.f};

  // loop-invariant B fragment offsets (XOR-swizzle matches setup image)
  int boff[6];
#pragma unroll
  for (int ct = 0; ct < 6; ++ct)
    boff[ct] = (hh * 1536 + (wc * 96 + ct * 16 + la) * 8) ^ (hh << 4);

  const int nst = K / 32;   // 32 (img) or 24 (txt) — always even

  auto issueBatch = [&](int s, float4& A0, float4& A1, float4& A2, float4& A3) {
    // 4 A loads first (longest latency), then 6 B gll: 10 vmem ops total
    const float* p0 = Ar0 + s * 32;
    const float* p1 = Ar1 + s * 32;
    A0 = *(const float4*)p0;
    A1 = *(const float4*)(p0 + 4);
    A2 = *(const float4*)p1;
    A3 = *(const float4*)(p1 + 4);
    const u16* src = wft + (size_t)s * 12288;
    char* dst = (char*)Bsm + (s % 3) * 24576;
#pragma unroll
    for (int i = 0; i < 6; ++i)
      gll16(src + i * 2048 + tid * 8, dst + i * 4096 + tid * 16);
  };

  // two named A register sets (even steps -> set0, odd -> set1); rule #20:
  // never index them with a runtime value.
  float4 e0, e1, e2, e3, o0, o1, o2, o3;

  auto body = [&](int s, float4& A0, float4& A1, float4& A2, float4& A3) {
    // top-of-step: batch(s) must be landed; batch(s+1) may stay in flight.
    if (s + 1 < nst) { WAITVM10(); } else { WAITVM0(); }
    SCHEDB();
    __builtin_amdgcn_s_barrier();
    SCHEDB();
    // split A(s) -> fragments (frees the reg set)
    bf16x8 fah[2], fal[2];
    {
      u16 h8[8], l8[8];
#pragma unroll
      for (int j = 0; j < 4; ++j) {
        split2(A0[j], h8[j], l8[j]);
        split2(A1[j], h8[4 + j], l8[4 + j]);
      }
      fah[0] = *(bf16x8*)h8; fal[0] = *(bf16x8*)l8;
#pragma unroll
      for (int j = 0; j < 4; ++j) {
        split2(A2[j], h8[j], l8[j]);
        split2(A3[j], h8[4 + j], l8[4 + j]);
      }
      fah[1] = *(bf16x8*)h8; fal[1] = *(bf16x8*)l8;
    }
    // issue batch(s+2) into the same reg set + buf[(s+2)%3]
    if (s + 2 < nst) issueBatch(s + 2, A0, A1, A2, A3);
    // B fragment reads (conflict-free, swizzled) + MFMA
    const u16* bb0 = Bsm + (s % 3) * 12288;
#pragma unroll
    for (int ct = 0; ct < 6; ++ct) {
      const bf16x8 fbh = *(const bf16x8*)&bb0[boff[ct]];
      const bf16x8 fbl = *(const bf16x8*)&bb0[6144 + boff[ct]];
#pragma unroll
      for (int rt = 0; rt < 2; ++rt) {
        acc[rt][ct] = __builtin_amdgcn_mfma_f32_16x16x32_bf16(fah[rt], fbh, acc[rt][ct], 0, 0, 0);
        acc[rt][ct] = __builtin_amdgcn_mfma_f32_16x16x32_bf16(fah[rt], fbl, acc[rt][ct], 0, 0, 0);
        acc[rt][ct] = __builtin_amdgcn_mfma_f32_16x16x32_bf16(fal[rt], fbh, acc[rt][ct], 0, 0, 0);
      }
    }
  };

  // prologue: batches 0 and 1 (20 vmem ops in flight)
  issueBatch(0, e0, e1, e2, e3);
  issueBatch(1, o0, o1, o2, o3);

  for (int s = 0; s < nst; s += 2) {
    body(s,     e0, e1, e2, e3);
    body(s + 1, o0, o1, o2, o3);
  }

  // epilogue: + bias, pack hi/lo u32, scatter to g_S in K2-fragment order
#pragma unroll
  for (int ct = 0; ct < 6; ++ct) {
    const int cg = wc * 6 + ct;
    const int fq = (cg >> 1) * 16 + la;
    const float bv = g_fp[fq * 8 + 4 + mod * 2 + (cg & 1)];
    const int ks = cg >> 1;
    const int khh = (cg & 1) * 2 + (la >> 3);
    const int j8 = la & 7;
    const size_t sbase = ((size_t)((mod * 6 + ks) * 4 + khh)) * MROWS;
#pragma unroll
    for (int rt = 0; rt < 2; ++rt) {
      const int rb = row0 + wr * 32 + rt * 16 + hh * 4;
#pragma unroll
      for (int j = 0; j < 4; ++j) {
        u16 h, l;
        split2(acc[rt][ct][j] + bv, h, l);
        g_S[(sbase + rb + j) * 8 + j8] = ((u32)h << 16) | l;
      }
    }
  }
}

// ---------------------------------------------------------------------------
// K2: mask (rot+AVRF+MSC, lane-local via shfl pairing) + iDFT via MFMA.
// 256 thr = 4 waves; wave = 16 rows x 128 out cols; Y stays in registers.
// ---------------------------------------------------------------------------
__global__ __launch_bounds__(256) void k2_idft(
    const float* __restrict__ lamw, float* __restrict__ out, int M) {
  __shared__ __align__(16) u16 Gs[8192];      // [plane2][gran4][n128][8] ^ swz
  __shared__ __align__(16) float fps[96 * 8]; // 3KB param table

  const int tid = threadIdx.x;
  const int lane = tid & 63, wv = tid >> 6;
  const int la = lane & 15, hh = lane >> 4;
  const int part = hh >> 1;                   // 0: re-lane, 1: im-lane
  const int row = blockIdx.x * 64 + wv * 16 + la;

  if (tid < 192) gll16((const char*)g_fp + tid * 16, (char*)fps + tid * 16);

  const float l0 = lamw[0], l1 = lamw[1];
  const float mx = fmaxf(l0, l1);
  const float e0 = expf(l0 - mx), e1 = expf(l1 - mx);
  const float lam0 = e0 / (e0 + e1), lam1 = e1 / (e0 + e1);

  f32x4 ai[8], at[8];
#pragma unroll
  for (int ct = 0; ct < 8; ++ct) {
    ai[ct] = (f32x4){0.f, 0.f, 0.f, 0.f};
    at[ct] = (f32x4){0.f, 0.f, 0.f, 0.f};
  }

  for (int ks = 0; ks < 6; ++ks) {
    // S loads (issue early; coalesced 512B per 16-lane quarter)
    const u32* si = &g_S[((size_t)((0 + ks) * 4 + hh) * MROWS + row) * 8];
    const u32* st = &g_S[((size_t)((24 + ks * 4) + hh) * MROWS + row) * 8];
    uint4 vi0 = *(const uint4*)si, vi1 = *(const uint4*)(si + 4);
    uint4 vt0 = *(const uint4*)st, vt1 = *(const uint4*)(st + 4);

    __syncthreads();                          // prev iter's G reads done
#pragma unroll
    for (int i = 0; i < 4; ++i)
      gll16((const char*)(g_gt + ks * 8192) + i * 4096 + tid * 16,
            (char*)Gs + i * 4096 + tid * 16);
    __syncthreads();                          // G (+fps) visible

    u32 vs_i[8], vs_t[8];
    *(uint4*)&vs_i[0] = vi0; *(uint4*)&vs_i[4] = vi1;
    *(uint4*)&vs_t[0] = vt0; *(uint4*)&vs_t[4] = vt1;

    const int fq0 = ks * 16 + (hh & 1) * 8;
    u16 yih[8], yil[8], yth[8], ytl[8];
#pragma unroll
    for (int j = 0; j < 8; ++j) {
      const f32x4 fpv = *(const f32x4*)&fps[(fq0 + j) * 8];  // rc, rs, avI, avT
      const float o_i = __uint_as_float(vs_i[j] & 0xFFFF0000u) + __uint_as_float(vs_i[j] << 16);
      const float o_t = __uint_as_float(vs_t[j] & 0xFFFF0000u) + __uint_as_float(vs_t[j] << 16);
      const float p_i = __shfl_xor(o_i, 32);
      const float p_t = __shfl_xor(o_t, 32);
      const float Sre_i = part ? p_i : o_i;
      const float Sim_i = part ? o_i : p_i;
      const float Sre_t = part ? p_t : o_t;
      const float Sim_t = part ? o_t : p_t;
      const float rc = fpv[0], rs = fpv[1];
      const float Air = Sre_i * rc + Sim_i * rs, Aii = Sim_i * rc - Sre_i * rs;  // * e^{-i phi}
      const float Atr = Sre_t * rc - Sim_t * rs, Ati = Sim_t * rc + Sre_t * rs;  // * conj
      const float cre = Air * Atr + Aii * Ati, cim = Aii * Atr - Air * Ati;
      const float pa = Air * Air + Aii * Aii, pb = Atr * Atr + Ati * Ati;
      const float msc = (cre * cre + cim * cim) / (pa * pb + 1e-8f);
      const float mi = lam0 * fpv[2] + lam1 * msc;
      const float mt = lam0 * fpv[3] + lam1 * msc;
      const float yi = (part ? Aii : Air) * mi;
      const float yt = (part ? Ati : Atr) * mt;
      split2(yi, yih[j], yil[j]);
      split2(yt, yth[j], ytl[j]);
    }
    const bf16x8 fih = *(bf16x8*)yih, fil = *(bf16x8*)yil;
    const bf16x8 fth = *(bf16x8*)yth, ftl = *(bf16x8*)ytl;
#pragma unroll
    for (int ct = 0; ct < 8; ++ct) {
      const int goff = (hh * 1024 + (ct * 16 + la) * 8) ^ (hh << 4);
      const bf16x8 gh = *(const bf16x8*)&Gs[goff];
      const bf16x8 gl = *(const bf16x8*)&Gs[4096 + goff];
      ai[ct] = __builtin_amdgcn_mfma_f32_16x16x32_bf16(fih, gh, ai[ct], 0, 0, 0);
      ai[ct] = __builtin_amdgcn_mfma_f32_16x16x32_bf16(fih, gl, ai[ct], 0, 0, 0);
      ai[ct] = __builtin_amdgcn_mfma_f32_16x16x32_bf16(fil, gh, ai[ct], 0, 0, 0);
      at[ct] = __builtin_amdgcn_mfma_f32_16x16x32_bf16(fth, gh, at[ct], 0, 0, 0);
      at[ct] = __builtin_amdgcn_mfma_f32_16x16x32_bf16(fth, gl, at[ct], 0, 0, 0);
      at[ct] = __builtin_amdgcn_mfma_f32_16x16x32_bf16(ftl, gh, at[ct], 0, 0, 0);
    }
  }

  float* oimg = out;
  float* otxt = out + (size_t)M * 128;
#pragma unroll
  for (int q = 0; q < 4; ++q) {
    const int orow = blockIdx.x * 64 + wv * 16 + hh * 4 + q;
    if (orow < M) {
#pragma unroll
      for (int ct = 0; ct < 8; ++ct) {
        oimg[(size_t)orow * 128 + ct * 16 + la] = ai[ct][q];
        otxt[(size_t)orow * 128 + ct * 16 + la] = at[ct][q];
      }
    }
  }
}

extern "C" void kernel_launch(void* const* d_in, const int* in_sizes, int n_in,
                              void* d_out, int out_size, void* d_ws, size_t ws_size,
                              hipStream_t stream) {
  const float* image_table = (const float*)d_in[2];
  const float* text_table  = (const float*)d_in[3];
  const float* W_img = (const float*)d_in[4];
  const float* b_img = (const float*)d_in[5];
  const float* W_txt = (const float*)d_in[6];
  const float* b_txt = (const float*)d_in[7];
  const float* avrf_img = (const float*)d_in[8];
  const float* avrf_txt = (const float*)d_in[9];
  const float* avg_R = (const float*)d_in[10];
  const float* psi = (const float*)d_in[11];
  const float* lamw = (const float*)d_in[12];

  const int M = in_sizes[0] / 128;        // 30000
  const int K_img = in_sizes[4] / 128;    // 1024
  const int K_txt = in_sizes[6] / 128;    // 768

  const int wft_threads = (K_img + K_txt) * 96;
  k_setup_wft<<<(wft_threads + 255) / 256, 256, 0, stream>>>(W_img, W_txt, K_img, K_txt);
  k_setup_gt<<<(192 * 128 + 255) / 256, 256, 0, stream>>>();
  k_setup_fp<<<2, 256, 0, stream>>>(b_img, b_txt, avrf_img, avrf_txt, avg_R, psi);

  const int bpm = (M + 63) / 64;          // 469
  k1_gemm<<<2 * bpm, 256, 0, stream>>>(image_table, text_table, M, K_img, K_txt, bpm);
  k2_idft<<<bpm, 256, 0, stream>>>(lamw, (float*)d_out, M);
}

// Round 10
// 136.449 us; speedup vs baseline: 1.7101x; 1.3012x over previous
//
#include <hip/hip_runtime.h>
#include <math.h>

typedef __bf16 bf16x8 __attribute__((ext_vector_type(8)));
typedef float f32x4 __attribute__((ext_vector_type(4)));
typedef unsigned short u16;
typedef unsigned int u32;

#define S128 0.08838834764831845f       // 1/sqrt(128)
#define TWOPI_128 0.04908738521234052f  // 2*pi/128
#define MROWS 30080                     // 235*128 (padded row capacity)

// ---------------------------------------------------------------------------
// Device-global precomputed operands.
// g_wft: per (mod, ks) chunk of 12288 u16 = [plane2][gran4][col192][8],
//        intra-plane offsets XOR-swizzled with (gran<<4) (u16 units).
// g_gt : per ks chunk of 8192 u16 = [plane2][gran4][n128][8], same swz.
// g_fp : per freq k (0..95): {rotc, rots, avrfI, avrfT, bIre, bIim, bTre, bTim}
// g_S  : spectra hi/lo packed u32, layout [mod][ks6][khh4][row MROWS][8]
// ---------------------------------------------------------------------------
__device__ __align__(16) u16 g_wft[56 * 12288];
__device__ __align__(16) u16 g_gt[6 * 8192];
__device__ __align__(16) float g_fp[96 * 8];
__device__ __align__(16) u32 g_S[(size_t)2 * 6 * 4 * MROWS * 8];

__device__ __forceinline__ void split2(float v, u16& h, u16& l) {
  unsigned u = __float_as_uint(v);
  h = (u16)(u >> 16);
  float hf = __uint_as_float(u & 0xFFFF0000u);
  float lo = v - hf;
  unsigned ul = __float_as_uint(lo);
  l = (u16)((ul + 0x7FFFu + ((ul >> 16) & 1u)) >> 16);
}

__device__ __forceinline__ void gll16(const void* gsrc, void* ldst) {
  __builtin_amdgcn_global_load_lds(
      (const __attribute__((address_space(1))) unsigned int*)gsrc,
      (__attribute__((address_space(3))) unsigned int*)ldst, 16, 0, 0);
}

// ---------------------------------------------------------------------------
// Setup: WF = W @ F (ortho rfft matrix), bf16 hi/lo, k-granule-major chunks,
// granule XOR-swizzle baked into the global image.
// ---------------------------------------------------------------------------
__global__ void k_setup_wft(const float* __restrict__ Wimg,
                            const float* __restrict__ Wtxt, int Kimg, int Ktxt) {
  int gid = blockIdx.x * 256 + threadIdx.x;
  int imgn = Kimg * 96;
  if (gid >= imgn + Ktxt * 96) return;
  const float* Wrow;
  u16* base;
  int kloc, fq;
  if (gid < imgn) {
    kloc = gid / 96; fq = gid % 96;
    Wrow = Wimg + (size_t)kloc * 128;
    base = g_wft + (size_t)(kloc >> 5) * 12288;
  } else {
    int l = gid - imgn;
    kloc = l / 96; fq = l % 96;
    Wrow = Wtxt + (size_t)kloc * 128;
    base = g_wft + (size_t)(32 + (kloc >> 5)) * 12288;
  }
  float re = 0.f, im = 0.f;
  if (fq <= 64) {
    float sts, stc;
    sincosf(TWOPI_128 * (float)fq, &sts, &stc);   // step e^{-ia} = (stc, -sts)
    for (int d0 = 0; d0 < 128; d0 += 16) {
      int m = (fq * d0) & 127;
      float sa, ca;
      sincosf(TWOPI_128 * (float)m, &sa, &ca);
      float cr = ca, ci = -sa;
      float wv[16];
      *(float4*)&wv[0]  = *(const float4*)&Wrow[d0];
      *(float4*)&wv[4]  = *(const float4*)&Wrow[d0 + 4];
      *(float4*)&wv[8]  = *(const float4*)&Wrow[d0 + 8];
      *(float4*)&wv[12] = *(const float4*)&Wrow[d0 + 12];
#pragma unroll
      for (int jj = 0; jj < 16; ++jj) {
        re = fmaf(wv[jj], cr, re);
        im = fmaf(wv[jj], ci, im);
        float nc = cr * stc + ci * sts;
        ci = ci * stc - cr * sts;
        cr = nc;
      }
    }
    re *= S128; im *= S128;
  }
  int gran = (kloc & 31) >> 3, j = kloc & 7;
  int cre = (fq >> 4) * 32 + (fq & 15);
  u16 h, l;
  split2(re, h, l);
  base[(gran * 1536 + cre * 8 + j) ^ (gran << 4)] = h;
  base[6144 + ((gran * 1536 + cre * 8 + j) ^ (gran << 4))] = l;
  split2(im, h, l);
  base[(gran * 1536 + (cre + 16) * 8 + j) ^ (gran << 4)] = h;
  base[6144 + ((gran * 1536 + (cre + 16) * 8 + j) ^ (gran << 4))] = l;
}

// G (ortho irfft): out[n] = S128 * sum_k ck*(Re cos + Im*(-sin)), ck={1,2,..,1}
__global__ void k_setup_gt(void) {
  int gid = blockIdx.x * 256 + threadIdx.x;
  if (gid >= 192 * 128) return;
  int pk = gid >> 7, n = gid & 127;
  int ks = pk >> 5, w = pk & 31, gran = (w >> 3) & 3, j = w & 7;
  int part = w >> 4, fl = ks * 16 + (w & 15);
  float val = 0.f;
  if (fl <= 64) {
    float ck = (fl == 0 || fl == 64) ? 1.f : 2.f;
    int m = (fl * n) & 127;
    float sa, ca;
    sincosf(TWOPI_128 * (float)m, &sa, &ca);
    val = (part == 0 ? ca : -sa) * ck * S128;
  }
  u16 h, l;
  split2(val, h, l);
  g_gt[ks * 8192 + ((gran * 1024 + n * 8 + j) ^ (gran << 4))] = h;
  g_gt[ks * 8192 + 4096 + ((gran * 1024 + n * 8 + j) ^ (gran << 4))] = l;
}

__global__ void k_setup_fp(const float* __restrict__ b_img, const float* __restrict__ b_txt,
                           const float* __restrict__ avrf_img, const float* __restrict__ avrf_txt,
                           const float* __restrict__ avg_R, const float* __restrict__ psi) {
  int gid = blockIdx.x * 256 + threadIdx.x;
  if (gid >= 96 * 4) return;
  int k = gid >> 2, q = gid & 3;
  float* fp = g_fp + k * 8;
  if (k > 64) {
    if (q == 0) { fp[0] = 1.f; fp[1] = 0.f; fp[2] = 0.f; fp[3] = 0.f; }
    fp[4 + q] = 0.f;
    return;
  }
  if (q == 0) {
    float phi = avg_R[k] * 0.5f + psi[k];
    float s, c;
    sincosf(phi, &s, &c);
    fp[0] = c; fp[1] = s; fp[2] = avrf_img[k]; fp[3] = avrf_txt[k];
  }
  const float* b = (q < 2) ? b_img : b_txt;
  int part = q & 1;
  float acc = 0.f;
  for (int d = 0; d < 128; ++d) {
    int m = (k * d) & 127;
    float sa, ca;
    sincosf(TWOPI_128 * (float)m, &sa, &ca);
    acc = fmaf(b[d], part ? -sa : ca, acc);
  }
  fp[4 + q] = acc * S128;
}

// ---------------------------------------------------------------------------
// K1: S = A @ WF + bF  (bf16 hi/lo split MFMA), pack hi/lo u32 -> g_S.
// Grid: [0, bpm) img, [bpm, 2*bpm) txt. 512 thr = 8 waves (4x2),
// BM=128: wave = 32 rows x 96 cols (2rt x 6ct fragments).
// R6 pipeline at 2x scale: barrier -> split+write A(s) -> barrier ->
// issue B(s+1) DMA + A(s+1) reg loads -> ds_read + 36 MFMA/wave.
// Per-step MFMA doubles vs BM=64 while barrier cost stays constant.
// LDS = 16KB A + 48KB B dbuf = 64KB -> 2 blocks/CU (16 waves/CU).
// ---------------------------------------------------------------------------
__global__ __launch_bounds__(512) void k1_gemm(
    const float* __restrict__ Aimg, const float* __restrict__ Atxt,
    int M, int Kimg, int Ktxt, int bpm) {
  __shared__ __align__(16) u16 Asm[2 * 4096];   // [plane2][gran4][row128][8] ^ swz
  __shared__ __align__(16) u16 Bsm[2 * 12288];  // dbuf x [plane2][gran4][col192][8] ^ swz

  const int bid = blockIdx.x;
  const int mod = bid >= bpm;
  const int bblk = mod ? bid - bpm : bid;
  const float* A = mod ? Atxt : Aimg;
  const int K = mod ? Ktxt : Kimg;
  const u16* wft = g_wft + (mod ? (size_t)32 * 12288 : 0);
  const int row0 = bblk * 128;

  const int tid = threadIdx.x;
  const int lane = tid & 63, wv = tid >> 6;
  const int la = lane & 15, hh = lane >> 4;
  const int wr = wv >> 1, wc = wv & 1;          // wr 0..3 (32-row strips), wc 0..1

  // A staging: thread -> (row rseg 0..127, k-granule g4)
  const int rseg = tid >> 2, g4 = tid & 3;
  const int awoff = (g4 * 1024 + rseg * 8) ^ (g4 << 4);   // swizzled write slot
  int grow = row0 + rseg;
  if (grow > M - 1) grow = M - 1;
  const float* Abase = A + (size_t)grow * K + g4 * 8;

  f32x4 acc[2][6];
#pragma unroll
  for (int rt = 0; rt < 2; ++rt)
#pragma unroll
    for (int ct = 0; ct < 6; ++ct) acc[rt][ct] = (f32x4){0.f, 0.f, 0.f, 0.f};

  // loop-invariant B fragment offsets (XOR-swizzle matches setup image)
  int boff[6];
#pragma unroll
  for (int ct = 0; ct < 6; ++ct)
    boff[ct] = (hh * 1536 + (wc * 96 + ct * 16 + la) * 8) ^ (hh << 4);

  const int nst = K / 32;

  auto stageB = [&](int s, int buf) {
    const u16* src = wft + (size_t)s * 12288;
    char* dst = (char*)Bsm + buf * 24576;
#pragma unroll
    for (int i = 0; i < 3; ++i)
      gll16(src + i * 4096 + tid * 8, dst + i * 8192 + tid * 16);
  };

  // prologue: B(0) DMA + A(0) reg loads
  stageB(0, 0);
  float4 av0 = *(const float4*)(Abase);
  float4 av1 = *(const float4*)(Abase + 4);

  for (int s = 0; s < nst; ++s) {
    const int cur = s & 1;
    __syncthreads();               // B(s) DMA landed; buf[cur^1]+Asm readers done
    {  // split A once -> LDS (k-granule-major, swizzled)
      u16 h8[8], l8[8];
      const float va[8] = {av0.x, av0.y, av0.z, av0.w, av1.x, av1.y, av1.z, av1.w};
#pragma unroll
      for (int j = 0; j < 8; ++j) split2(va[j], h8[j], l8[j]);
      *(bf16x8*)&Asm[awoff] = *(bf16x8*)h8;
      *(bf16x8*)&Asm[4096 + awoff] = *(bf16x8*)l8;
    }
    __syncthreads();               // A visible (no vmem outstanding here)

    if (s + 1 < nst) {             // prefetch: overlaps the MFMA phase below
      stageB(s + 1, cur ^ 1);
      av0 = *(const float4*)(Abase + (s + 1) * 32);
      av1 = *(const float4*)(Abase + (s + 1) * 32 + 4);
    }

    // fragment reads + MFMA
    bf16x8 fah[2], fal[2];
#pragma unroll
    for (int rt = 0; rt < 2; ++rt) {
      const int ar = wr * 32 + rt * 16 + la;
      const int off = (hh * 1024 + ar * 8) ^ (hh << 4);
      fah[rt] = *(const bf16x8*)&Asm[off];
      fal[rt] = *(const bf16x8*)&Asm[4096 + off];
    }
    const u16* bb0 = Bsm + cur * 12288;
#pragma unroll
    for (int ct = 0; ct < 6; ++ct) {
      const bf16x8 fbh = *(const bf16x8*)&bb0[boff[ct]];
      const bf16x8 fbl = *(const bf16x8*)&bb0[6144 + boff[ct]];
#pragma unroll
      for (int rt = 0; rt < 2; ++rt) {
        acc[rt][ct] = __builtin_amdgcn_mfma_f32_16x16x32_bf16(fah[rt], fbh, acc[rt][ct], 0, 0, 0);
        acc[rt][ct] = __builtin_amdgcn_mfma_f32_16x16x32_bf16(fah[rt], fbl, acc[rt][ct], 0, 0, 0);
        acc[rt][ct] = __builtin_amdgcn_mfma_f32_16x16x32_bf16(fal[rt], fbh, acc[rt][ct], 0, 0, 0);
      }
    }
  }

  // epilogue: + bias, pack hi/lo u32, scatter to g_S in K2-fragment order
#pragma unroll
  for (int ct = 0; ct < 6; ++ct) {
    const int cg = wc * 6 + ct;
    const int fq = (cg >> 1) * 16 + la;
    const float bv = g_fp[fq * 8 + 4 + mod * 2 + (cg & 1)];
    const int ks = cg >> 1;
    const int khh = (cg & 1) * 2 + (la >> 3);
    const int j8 = la & 7;
    const size_t sbase = ((size_t)((mod * 6 + ks) * 4 + khh)) * MROWS;
#pragma unroll
    for (int rt = 0; rt < 2; ++rt) {
      const int rb = row0 + wr * 32 + rt * 16 + hh * 4;
#pragma unroll
      for (int j = 0; j < 4; ++j) {
        u16 h, l;
        split2(acc[rt][ct][j] + bv, h, l);
        g_S[(sbase + rb + j) * 8 + j8] = ((u32)h << 16) | l;
      }
    }
  }
}

// ---------------------------------------------------------------------------
// K2: mask (rot+AVRF+MSC, lane-local via shfl pairing) + iDFT via MFMA.
// 256 thr = 4 waves; wave = 16 rows x 128 out cols; Y stays in registers.
// ---------------------------------------------------------------------------
__global__ __launch_bounds__(256) void k2_idft(
    const float* __restrict__ lamw, float* __restrict__ out, int M) {
  __shared__ __align__(16) u16 Gs[8192];      // [plane2][gran4][n128][8] ^ swz
  __shared__ __align__(16) float fps[96 * 8]; // 3KB param table

  const int tid = threadIdx.x;
  const int lane = tid & 63, wv = tid >> 6;
  const int la = lane & 15, hh = lane >> 4;
  const int part = hh >> 1;                   // 0: re-lane, 1: im-lane
  const int row = blockIdx.x * 64 + wv * 16 + la;

  if (tid < 192) gll16((const char*)g_fp + tid * 16, (char*)fps + tid * 16);

  const float l0 = lamw[0], l1 = lamw[1];
  const float mx = fmaxf(l0, l1);
  const float e0 = expf(l0 - mx), e1 = expf(l1 - mx);
  const float lam0 = e0 / (e0 + e1), lam1 = e1 / (e0 + e1);

  f32x4 ai[8], at[8];
#pragma unroll
  for (int ct = 0; ct < 8; ++ct) {
    ai[ct] = (f32x4){0.f, 0.f, 0.f, 0.f};
    at[ct] = (f32x4){0.f, 0.f, 0.f, 0.f};
  }

  for (int ks = 0; ks < 6; ++ks) {
    // S loads (issue early; coalesced 512B per 16-lane quarter)
    const u32* si = &g_S[((size_t)((0 + ks) * 4 + hh) * MROWS + row) * 8];
    const u32* st = &g_S[((size_t)((24 + ks * 4) + hh) * MROWS + row) * 8];
    uint4 vi0 = *(const uint4*)si, vi1 = *(const uint4*)(si + 4);
    uint4 vt0 = *(const uint4*)st, vt1 = *(const uint4*)(st + 4);

    __syncthreads();                          // prev iter's G reads done
#pragma unroll
    for (int i = 0; i < 4; ++i)
      gll16((const char*)(g_gt + ks * 8192) + i * 4096 + tid * 16,
            (char*)Gs + i * 4096 + tid * 16);
    __syncthreads();                          // G (+fps) visible

    u32 vs_i[8], vs_t[8];
    *(uint4*)&vs_i[0] = vi0; *(uint4*)&vs_i[4] = vi1;
    *(uint4*)&vs_t[0] = vt0; *(uint4*)&vs_t[4] = vt1;

    const int fq0 = ks * 16 + (hh & 1) * 8;
    u16 yih[8], yil[8], yth[8], ytl[8];
#pragma unroll
    for (int j = 0; j < 8; ++j) {
      const f32x4 fpv = *(const f32x4*)&fps[(fq0 + j) * 8];  // rc, rs, avI, avT
      const float o_i = __uint_as_float(vs_i[j] & 0xFFFF0000u) + __uint_as_float(vs_i[j] << 16);
      const float o_t = __uint_as_float(vs_t[j] & 0xFFFF0000u) + __uint_as_float(vs_t[j] << 16);
      const float p_i = __shfl_xor(o_i, 32);
      const float p_t = __shfl_xor(o_t, 32);
      const float Sre_i = part ? p_i : o_i;
      const float Sim_i = part ? o_i : p_i;
      const float Sre_t = part ? p_t : o_t;
      const float Sim_t = part ? o_t : p_t;
      const float rc = fpv[0], rs = fpv[1];
      const float Air = Sre_i * rc + Sim_i * rs, Aii = Sim_i * rc - Sre_i * rs;  // * e^{-i phi}
      const float Atr = Sre_t * rc - Sim_t * rs, Ati = Sim_t * rc + Sre_t * rs;  // * conj
      const float cre = Air * Atr + Aii * Ati, cim = Aii * Atr - Air * Ati;
      const float pa = Air * Air + Aii * Aii, pb = Atr * Atr + Ati * Ati;
      const float msc = (cre * cre + cim * cim) / (pa * pb + 1e-8f);
      const float mi = lam0 * fpv[2] + lam1 * msc;
      const float mt = lam0 * fpv[3] + lam1 * msc;
      const float yi = (part ? Aii : Air) * mi;
      const float yt = (part ? Ati : Atr) * mt;
      split2(yi, yih[j], yil[j]);
      split2(yt, yth[j], ytl[j]);
    }
    const bf16x8 fih = *(bf16x8*)yih, fil = *(bf16x8*)yil;
    const bf16x8 fth = *(bf16x8*)yth, ftl = *(bf16x8*)ytl;
#pragma unroll
    for (int ct = 0; ct < 8; ++ct) {
      const int goff = (hh * 1024 + (ct * 16 + la) * 8) ^ (hh << 4);
      const bf16x8 gh = *(const bf16x8*)&Gs[goff];
      const bf16x8 gl = *(const bf16x8*)&Gs[4096 + goff];
      ai[ct] = __builtin_amdgcn_mfma_f32_16x16x32_bf16(fih, gh, ai[ct], 0, 0, 0);
      ai[ct] = __builtin_amdgcn_mfma_f32_16x16x32_bf16(fih, gl, ai[ct], 0, 0, 0);
      ai[ct] = __builtin_amdgcn_mfma_f32_16x16x32_bf16(fil, gh, ai[ct], 0, 0, 0);
      at[ct] = __builtin_amdgcn_mfma_f32_16x16x32_bf16(fth, gh, at[ct], 0, 0, 0);
      at[ct] = __builtin_amdgcn_mfma_f32_16x16x32_bf16(fth, gl, at[ct], 0, 0, 0);
      at[ct] = __builtin_amdgcn_mfma_f32_16x16x32_bf16(ftl, gh, at[ct], 0, 0, 0);
    }
  }

  float* oimg = out;
  float* otxt = out + (size_t)M * 128;
#pragma unroll
  for (int q = 0; q < 4; ++q) {
    const int orow = blockIdx.x * 64 + wv * 16 + hh * 4 + q;
    if (orow < M) {
#pragma unroll
      for (int ct = 0; ct < 8; ++ct) {
        oimg[(size_t)orow * 128 + ct * 16 + la] = ai[ct][q];
        otxt[(size_t)orow * 128 + ct * 16 + la] = at[ct][q];
      }
    }
  }
}

extern "C" void kernel_launch(void* const* d_in, const int* in_sizes, int n_in,
                              void* d_out, int out_size, void* d_ws, size_t ws_size,
                              hipStream_t stream) {
  const float* image_table = (const float*)d_in[2];
  const float* text_table  = (const float*)d_in[3];
  const float* W_img = (const float*)d_in[4];
  const float* b_img = (const float*)d_in[5];
  const float* W_txt = (const float*)d_in[6];
  const float* b_txt = (const float*)d_in[7];
  const float* avrf_img = (const float*)d_in[8];
  const float* avrf_txt = (const float*)d_in[9];
  const float* avg_R = (const float*)d_in[10];
  const float* psi = (const float*)d_in[11];
  const float* lamw = (const float*)d_in[12];

  const int M = in_sizes[0] / 128;        // 30000
  const int K_img = in_sizes[4] / 128;    // 1024
  const int K_txt = in_sizes[6] / 128;    // 768

  const int wft_threads = (K_img + K_txt) * 96;
  k_setup_wft<<<(wft_threads + 255) / 256, 256, 0, stream>>>(W_img, W_txt, K_img, K_txt);
  k_setup_gt<<<(192 * 128 + 255) / 256, 256, 0, stream>>>();
  k_setup_fp<<<2, 256, 0, stream>>>(b_img, b_txt, avrf_img, avrf_txt, avg_R, psi);

  const int bpm = (M + 127) / 128;        // 235
  k1_gemm<<<2 * bpm, 512, 0, stream>>>(image_table, text_table, M, K_img, K_txt, bpm);
  k2_idft<<<(M + 63) / 64, 256, 0, stream>>>(lamw, (float*)d_out, M);
}